// Round 1
// baseline (208.994 us; speedup 1.0000x reference)
//
#include <hip/hip_runtime.h>
#include <math.h>

namespace {

constexpr int Bdim  = 4096;
constexpr int D_IN  = 2048;
constexpr int D_CTX = 512;
constexpr int UNITS = 2048;
constexpr int RANK  = 256;

constexpr int BM = 64, BN = 64, BK = 16;

// ---------------------------------------------------------------------------
// Kernel 1: s[b,r] = S[r] * sigmoid( (context @ W)[b,r] + Bc[r] )
//   A = context [M=4096, K=512] row-major, B = W [K=512, N=256] row-major
// ---------------------------------------------------------------------------
__global__ __launch_bounds__(256) void k_gate(
    const float* __restrict__ ctx, const float* __restrict__ W,
    const float* __restrict__ S,   const float* __restrict__ Bc,
    float* __restrict__ s_out) {
  constexpr int M = Bdim, N = RANK, K = D_CTX;
  __shared__ float As[BK][BM];
  __shared__ float Bs[BK][BN];
  const int t  = threadIdx.x;
  const int bm = blockIdx.x * BM;
  const int bn = blockIdx.y * BN;
  const int tx = t & 15, ty = t >> 4;
  float acc[4][4] = {};
  for (int k0 = 0; k0 < K; k0 += BK) {
    {
      const int row = t >> 2;
      const int kq  = (t & 3) << 2;
      float4 v = *(const float4*)(ctx + (size_t)(bm + row) * K + k0 + kq);
      As[kq + 0][row] = v.x; As[kq + 1][row] = v.y;
      As[kq + 2][row] = v.z; As[kq + 3][row] = v.w;
    }
    {
      const int kr = t >> 4;
      const int nq = (t & 15) << 2;
      *(float4*)&Bs[kr][nq] = *(const float4*)(W + (size_t)(k0 + kr) * N + bn + nq);
    }
    __syncthreads();
#pragma unroll
    for (int k = 0; k < BK; ++k) {
      float a[4], b[4];
#pragma unroll
      for (int i = 0; i < 4; ++i) a[i] = As[k][ty * 4 + i];
#pragma unroll
      for (int j = 0; j < 4; ++j) b[j] = Bs[k][tx * 4 + j];
#pragma unroll
      for (int i = 0; i < 4; ++i)
#pragma unroll
        for (int j = 0; j < 4; ++j) acc[i][j] += a[i] * b[j];
    }
    __syncthreads();
  }
#pragma unroll
  for (int i = 0; i < 4; ++i) {
    const int m = bm + ty * 4 + i;
#pragma unroll
    for (int j = 0; j < 4; ++j) {
      const int r   = bn + tx * 4 + j;
      const float h = acc[i][j] + Bc[r];
      const float sig = 1.0f / (1.0f + expf(-h));
      s_out[(size_t)m * N + r] = S[r] * sig;
    }
  }
}

// ---------------------------------------------------------------------------
// Kernel 2: proj[b,r] = (inputs @ U)[b,r] * s[b,r]
//   A = inputs [M=4096, K=2048], B = U [K=2048, N=256] row-major
// ---------------------------------------------------------------------------
__global__ __launch_bounds__(256) void k_proj(
    const float* __restrict__ X, const float* __restrict__ U,
    const float* __restrict__ s_in, float* __restrict__ proj) {
  constexpr int M = Bdim, N = RANK, K = D_IN;
  __shared__ float As[BK][BM];
  __shared__ float Bs[BK][BN];
  const int t  = threadIdx.x;
  const int bm = blockIdx.x * BM;
  const int bn = blockIdx.y * BN;
  const int tx = t & 15, ty = t >> 4;
  float acc[4][4] = {};
  for (int k0 = 0; k0 < K; k0 += BK) {
    {
      const int row = t >> 2;
      const int kq  = (t & 3) << 2;
      float4 v = *(const float4*)(X + (size_t)(bm + row) * K + k0 + kq);
      As[kq + 0][row] = v.x; As[kq + 1][row] = v.y;
      As[kq + 2][row] = v.z; As[kq + 3][row] = v.w;
    }
    {
      const int kr = t >> 4;
      const int nq = (t & 15) << 2;
      *(float4*)&Bs[kr][nq] = *(const float4*)(U + (size_t)(k0 + kr) * N + bn + nq);
    }
    __syncthreads();
#pragma unroll
    for (int k = 0; k < BK; ++k) {
      float a[4], b[4];
#pragma unroll
      for (int i = 0; i < 4; ++i) a[i] = As[k][ty * 4 + i];
#pragma unroll
      for (int j = 0; j < 4; ++j) b[j] = Bs[k][tx * 4 + j];
#pragma unroll
      for (int i = 0; i < 4; ++i)
#pragma unroll
        for (int j = 0; j < 4; ++j) acc[i][j] += a[i] * b[j];
    }
    __syncthreads();
  }
#pragma unroll
  for (int i = 0; i < 4; ++i) {
    const int m = bm + ty * 4 + i;
#pragma unroll
    for (int j = 0; j < 4; ++j) {
      const int r = bn + tx * 4 + j;
      proj[(size_t)m * N + r] = acc[i][j] * s_in[(size_t)m * N + r];
    }
  }
}

// ---------------------------------------------------------------------------
// Kernel 3: out[b,m] = (proj @ V^T)[b,m] + bias[m]
//   A = proj [M=4096, K=256], B = V [N=2048 rows, K=256] (transposed-B GEMM)
// ---------------------------------------------------------------------------
__global__ __launch_bounds__(256) void k_out(
    const float* __restrict__ P, const float* __restrict__ V,
    const float* __restrict__ bias, float* __restrict__ out) {
  constexpr int M = Bdim, N = UNITS, K = RANK;
  __shared__ float As[BK][BM];
  __shared__ float Bs[BK][BN];
  const int t  = threadIdx.x;
  const int bm = blockIdx.x * BM;
  const int bn = blockIdx.y * BN;
  const int tx = t & 15, ty = t >> 4;
  float acc[4][4] = {};
  for (int k0 = 0; k0 < K; k0 += BK) {
    {
      const int row = t >> 2;
      const int kq  = (t & 3) << 2;
      float4 v = *(const float4*)(P + (size_t)(bm + row) * K + k0 + kq);
      As[kq + 0][row] = v.x; As[kq + 1][row] = v.y;
      As[kq + 2][row] = v.z; As[kq + 3][row] = v.w;
    }
    {
      const int nrow = t >> 2;
      const int kq   = (t & 3) << 2;
      float4 v = *(const float4*)(V + (size_t)(bn + nrow) * K + k0 + kq);
      Bs[kq + 0][nrow] = v.x; Bs[kq + 1][nrow] = v.y;
      Bs[kq + 2][nrow] = v.z; Bs[kq + 3][nrow] = v.w;
    }
    __syncthreads();
#pragma unroll
    for (int k = 0; k < BK; ++k) {
      float a[4], b[4];
#pragma unroll
      for (int i = 0; i < 4; ++i) a[i] = As[k][ty * 4 + i];
#pragma unroll
      for (int j = 0; j < 4; ++j) b[j] = Bs[k][tx * 4 + j];
#pragma unroll
      for (int i = 0; i < 4; ++i)
#pragma unroll
        for (int j = 0; j < 4; ++j) acc[i][j] += a[i] * b[j];
    }
    __syncthreads();
  }
#pragma unroll
  for (int i = 0; i < 4; ++i) {
    const int m = bm + ty * 4 + i;
#pragma unroll
    for (int j = 0; j < 4; ++j) {
      const int n = bn + tx * 4 + j;
      out[(size_t)m * N + n] = acc[i][j] + bias[n];
    }
  }
}

}  // namespace

extern "C" void kernel_launch(void* const* d_in, const int* in_sizes, int n_in,
                              void* d_out, int out_size, void* d_ws, size_t ws_size,
                              hipStream_t stream) {
  const float* inputs  = (const float*)d_in[0];  // [4096, 2048]
  const float* context = (const float*)d_in[1];  // [4096, 512]
  const float* U       = (const float*)d_in[2];  // [2048, 256]
  const float* S       = (const float*)d_in[3];  // [256]
  const float* V       = (const float*)d_in[4];  // [2048, 256]
  const float* W       = (const float*)d_in[5];  // [512, 256]
  const float* Bc      = (const float*)d_in[6];  // [256]
  const float* bias    = (const float*)d_in[7];  // [2048]
  float* out = (float*)d_out;                    // [4096, 2048]

  float* s_buf = (float*)d_ws;                         // 4096*256 f32 = 4 MB
  float* proj  = s_buf + (size_t)Bdim * RANK;          // 4096*256 f32 = 4 MB

  dim3 block(256);
  k_gate<<<dim3(Bdim / BM, RANK / BN),  block, 0, stream>>>(context, W, S, Bc, s_buf);
  k_proj<<<dim3(Bdim / BM, RANK / BN),  block, 0, stream>>>(inputs, U, s_buf, proj);
  k_out <<<dim3(Bdim / BM, UNITS / BN), block, 0, stream>>>(proj, V, bias, out);
}

// Round 2
// 113.763 us; speedup vs baseline: 1.8371x; 1.8371x over previous
//
#include <hip/hip_runtime.h>
#include <math.h>

namespace {

constexpr int Bdim  = 4096;
constexpr int D_IN  = 2048;
constexpr int D_CTX = 512;
constexpr int UNITS = 2048;
constexpr int RANK  = 256;

typedef __bf16 bf16x8 __attribute__((ext_vector_type(8)));
typedef float  f32x4  __attribute__((ext_vector_type(4)));

// ---------------------------------------------------------------------------
// Prep: Ut[256][2048] = bf16(U^T), Wt[256][512] = bf16(W^T), Vb = bf16(V)
// grid (128, 3), 256 threads
// ---------------------------------------------------------------------------
__global__ __launch_bounds__(256) void k_prep(
    const float* __restrict__ U, const float* __restrict__ W,
    const float* __restrict__ V,
    __bf16* __restrict__ Ut, __bf16* __restrict__ Wt, __bf16* __restrict__ Vb) {
  const int job = blockIdx.y;
  const int t = threadIdx.x;
  if (job == 2) {  // straight convert V [2048*256]
    const size_t n = (size_t)UNITS * RANK;
    for (size_t i = ((size_t)blockIdx.x * 256 + t) * 4; i < n; i += (size_t)128 * 256 * 4) {
      float4 v = *(const float4*)(V + i);
      Vb[i + 0] = (__bf16)v.x; Vb[i + 1] = (__bf16)v.y;
      Vb[i + 2] = (__bf16)v.z; Vb[i + 3] = (__bf16)v.w;
    }
    return;
  }
  const float* src = job ? W : U;
  __bf16* dst      = job ? Wt : Ut;
  const int K = job ? D_CTX : D_IN;   // rows of src
  const int tilesK = K / 64;
  const int tid = blockIdx.x;
  if (tid >= tilesK * 4) return;      // N=256 -> 4 col tiles
  const int k0 = (tid % tilesK) * 64;
  const int n0 = (tid / tilesK) * 64;
  __shared__ __bf16 T[64][72];        // [n][k], pitch 144B (16B-aligned)
  const int i  = t >> 4;              // src row in tile (step 16)
  const int j4 = (t & 15) * 4;        // src col
  for (int ii = i; ii < 64; ii += 16) {
    float4 v = *(const float4*)(src + (size_t)(k0 + ii) * RANK + n0 + j4);
    T[j4 + 0][ii] = (__bf16)v.x;
    T[j4 + 1][ii] = (__bf16)v.y;
    T[j4 + 2][ii] = (__bf16)v.z;
    T[j4 + 3][ii] = (__bf16)v.w;
  }
  __syncthreads();
  const int jj = t >> 3;              // out row in tile (step 32)
  const int c  = t & 7;               // 16B chunk
  for (int j2 = jj; j2 < 64; j2 += 32) {
    bf16x8 v = *(const bf16x8*)&T[j2][c * 8];
    *(bf16x8*)(dst + (size_t)(n0 + j2) * K + k0 + c * 8) = v;
  }
}

// ---------------------------------------------------------------------------
// Templated bf16-MFMA GEMM, B given transposed: C[M][N] = A[M][K] @ Bt[N][K]^T
//   mfma_f32_16x16x32_bf16. LDS tiles XOR-swizzled (byte ^= (row&7)<<4).
//   EPI 0: s = bf16( S[n] * sigmoid(val + Bc[n]) )
//   EPI 1: proj = bf16( val * s[m,n] )
//   EPI 2: out  = f32 ( val + bias[n] )
// ---------------------------------------------------------------------------
template <int BM, int BN, int BK, int WAVES_M, int WAVES_N, bool A_F32, int EPI>
__global__ __launch_bounds__(256) void gemm_bt(
    const void* __restrict__ Ap, const __bf16* __restrict__ Bt,
    void* __restrict__ Cp, const float* __restrict__ e0,
    const float* __restrict__ e1, const __bf16* __restrict__ s_in,
    int Mt, int Nt, int Kt) {
  constexpr int FM = BM / WAVES_M / 16;
  constexpr int FN = BN / WAVES_N / 16;
  static_assert(WAVES_M * WAVES_N == 4, "4 waves");
  static_assert(BK == 64, "row = 128B");
  __shared__ __align__(16) __bf16 As[BM * BK];
  __shared__ __align__(16) __bf16 Bs[BN * BK];
  const int t  = threadIdx.x;
  const int bm = blockIdx.x * BM;
  const int bn = blockIdx.y * BN;
  const int w = t >> 6, l = t & 63;
  const int wr0 = (w / WAVES_N) * (FM * 16);
  const int wc0 = (w % WAVES_N) * (FN * 16);
  const int lrow = l & 15;
  const int lk   = l >> 4;
  f32x4 acc[FM][FN] = {};

  for (int k0 = 0; k0 < Kt; k0 += BK) {
    if (A_F32) {
      const float* A = (const float*)Ap;
#pragma unroll
      for (int c = t; c < BM * 8; c += 256) {
        const int row = c >> 3, kc = c & 7;
        const float* g = A + (size_t)(bm + row) * Kt + k0 + kc * 8;
        float4 lo = *(const float4*)g;
        float4 hi = *(const float4*)(g + 4);
        bf16x8 v;
        v[0] = (__bf16)lo.x; v[1] = (__bf16)lo.y; v[2] = (__bf16)lo.z; v[3] = (__bf16)lo.w;
        v[4] = (__bf16)hi.x; v[5] = (__bf16)hi.y; v[6] = (__bf16)hi.z; v[7] = (__bf16)hi.w;
        *(bf16x8*)((char*)As + row * 128 + ((kc ^ (row & 7)) * 16)) = v;
      }
    } else {
      const __bf16* A = (const __bf16*)Ap;
#pragma unroll
      for (int c = t; c < BM * 8; c += 256) {
        const int row = c >> 3, kc = c & 7;
        bf16x8 v = *(const bf16x8*)(A + (size_t)(bm + row) * Kt + k0 + kc * 8);
        *(bf16x8*)((char*)As + row * 128 + ((kc ^ (row & 7)) * 16)) = v;
      }
    }
#pragma unroll
    for (int c = t; c < BN * 8; c += 256) {
      const int row = c >> 3, kc = c & 7;
      bf16x8 v = *(const bf16x8*)(Bt + (size_t)(bn + row) * Kt + k0 + kc * 8);
      *(bf16x8*)((char*)Bs + row * 128 + ((kc ^ (row & 7)) * 16)) = v;
    }
    __syncthreads();
#pragma unroll
    for (int kk = 0; kk < BK / 32; ++kk) {
      bf16x8 af[FM], bfr[FN];
#pragma unroll
      for (int mf = 0; mf < FM; ++mf) {
        const int row = wr0 + mf * 16 + lrow;
        af[mf] = *(const bf16x8*)((const char*)As + row * 128 +
                                  (((kk * 4 + lk) ^ (row & 7)) * 16));
      }
#pragma unroll
      for (int nf = 0; nf < FN; ++nf) {
        const int row = wc0 + nf * 16 + lrow;
        bfr[nf] = *(const bf16x8*)((const char*)Bs + row * 128 +
                                   (((kk * 4 + lk) ^ (row & 7)) * 16));
      }
#pragma unroll
      for (int mf = 0; mf < FM; ++mf)
#pragma unroll
        for (int nf = 0; nf < FN; ++nf)
          acc[mf][nf] = __builtin_amdgcn_mfma_f32_16x16x32_bf16(
              af[mf], bfr[nf], acc[mf][nf], 0, 0, 0);
    }
    __syncthreads();
  }

#pragma unroll
  for (int mf = 0; mf < FM; ++mf) {
#pragma unroll
    for (int nf = 0; nf < FN; ++nf) {
#pragma unroll
      for (int r = 0; r < 4; ++r) {
        const int m = bm + wr0 + mf * 16 + (l >> 4) * 4 + r;
        const int n = bn + wc0 + nf * 16 + (l & 15);
        const float val = acc[mf][nf][r];
        if (EPI == 0) {
          const float h  = val + e1[n];
          const float sg = 1.0f / (1.0f + __expf(-h));
          ((__bf16*)Cp)[(size_t)m * Nt + n] = (__bf16)(e0[n] * sg);
        } else if (EPI == 1) {
          const float sv = (float)s_in[(size_t)m * Nt + n];
          ((__bf16*)Cp)[(size_t)m * Nt + n] = (__bf16)(val * sv);
        } else {
          ((float*)Cp)[(size_t)m * Nt + n] = val + e0[n];
        }
      }
    }
  }
}

}  // namespace

extern "C" void kernel_launch(void* const* d_in, const int* in_sizes, int n_in,
                              void* d_out, int out_size, void* d_ws, size_t ws_size,
                              hipStream_t stream) {
  const float* inputs  = (const float*)d_in[0];  // [4096, 2048]
  const float* context = (const float*)d_in[1];  // [4096, 512]
  const float* U       = (const float*)d_in[2];  // [2048, 256]
  const float* S       = (const float*)d_in[3];  // [256]
  const float* V       = (const float*)d_in[4];  // [2048, 256]
  const float* W       = (const float*)d_in[5];  // [512, 256]
  const float* Bc      = (const float*)d_in[6];  // [256]
  const float* bias    = (const float*)d_in[7];  // [2048]
  float* out = (float*)d_out;                    // [4096, 2048]

  char* ws = (char*)d_ws;
  __bf16* Ut   = (__bf16*)(ws);                       // 256x2048  (1 MB)
  __bf16* Wt   = (__bf16*)(ws + 1048576);             // 256x512   (256 KB)
  __bf16* Vb   = (__bf16*)(ws + 1310720);             // 2048x256  (1 MB)
  __bf16* sbuf = (__bf16*)(ws + 2359296);             // 4096x256  (2 MB)
  __bf16* proj = (__bf16*)(ws + 4456448);             // 4096x256  (2 MB)

  k_prep<<<dim3(128, 3), 256, 0, stream>>>(U, W, V, Ut, Wt, Vb);

  // s = bf16( S * sigmoid(ctx @ W + Bc) )      [4096 x 256], K=512
  gemm_bt<32, 256, 64, 1, 4, true, 0><<<dim3(Bdim / 32, 1), 256, 0, stream>>>(
      context, Wt, sbuf, S, Bc, nullptr, Bdim, RANK, D_CTX);

  // proj = bf16( (x @ U) * s )                 [4096 x 256], K=2048
  gemm_bt<32, 256, 64, 1, 4, true, 1><<<dim3(Bdim / 32, 1), 256, 0, stream>>>(
      inputs, Ut, proj, nullptr, nullptr, sbuf, Bdim, RANK, D_IN);

  // out = proj @ V^T + bias                    [4096 x 2048], K=256
  gemm_bt<128, 128, 64, 2, 2, false, 2><<<dim3(Bdim / 128, UNITS / 128), 256, 0, stream>>>(
      proj, Vb, out, bias, nullptr, nullptr, Bdim, UNITS, RANK);
}

// Round 3
// 65.108 us; speedup vs baseline: 3.2099x; 1.7473x over previous
//
#include <hip/hip_runtime.h>
#include <math.h>

namespace {

constexpr int Bdim  = 4096;
constexpr int D_IN  = 2048;
constexpr int D_CTX = 512;
constexpr int UNITS = 2048;
constexpr int RANK  = 256;

typedef __bf16 bf16x8 __attribute__((ext_vector_type(8)));
typedef __bf16 bf16x4 __attribute__((ext_vector_type(4)));
typedef float  f32x4  __attribute__((ext_vector_type(4)));

// ---------------------------------------------------------------------------
// Prep: Ut[256][2048] = bf16(U^T), Wt[256][512] = bf16(W^T), Vb = bf16(V)
// ---------------------------------------------------------------------------
__global__ __launch_bounds__(256) void k_prep(
    const float* __restrict__ U, const float* __restrict__ W,
    const float* __restrict__ V,
    __bf16* __restrict__ Ut, __bf16* __restrict__ Wt, __bf16* __restrict__ Vb) {
  const int job = blockIdx.y;
  const int t = threadIdx.x;
  if (job == 2) {  // straight convert V [2048*256]
    const size_t n = (size_t)UNITS * RANK;
    for (size_t i = ((size_t)blockIdx.x * 256 + t) * 4; i < n; i += (size_t)128 * 256 * 4) {
      float4 v = *(const float4*)(V + i);
      Vb[i + 0] = (__bf16)v.x; Vb[i + 1] = (__bf16)v.y;
      Vb[i + 2] = (__bf16)v.z; Vb[i + 3] = (__bf16)v.w;
    }
    return;
  }
  const float* src = job ? W : U;
  __bf16* dst      = job ? Wt : Ut;
  const int K = job ? D_CTX : D_IN;   // rows of src
  const int tilesK = K / 64;
  const int tid = blockIdx.x;
  if (tid >= tilesK * 4) return;      // N=256 -> 4 col tiles
  const int k0 = (tid % tilesK) * 64;
  const int n0 = (tid / tilesK) * 64;
  __shared__ __bf16 T[64][72];        // [n][k], pitch 144B (16B-aligned)
  const int i  = t >> 4;              // src row in tile (step 16)
  const int j4 = (t & 15) * 4;        // src col
  for (int ii = i; ii < 64; ii += 16) {
    float4 v = *(const float4*)(src + (size_t)(k0 + ii) * RANK + n0 + j4);
    T[j4 + 0][ii] = (__bf16)v.x;
    T[j4 + 1][ii] = (__bf16)v.y;
    T[j4 + 2][ii] = (__bf16)v.z;
    T[j4 + 3][ii] = (__bf16)v.w;
  }
  __syncthreads();
  const int jj = t >> 3;              // out row in tile (step 32)
  const int c  = t & 7;               // 16B chunk
  for (int j2 = jj; j2 < 64; j2 += 32) {
    bf16x8 v = *(const bf16x8*)&T[j2][c * 8];
    *(bf16x8*)(dst + (size_t)(n0 + j2) * K + k0 + c * 8) = v;
  }
}

// ---------------------------------------------------------------------------
// Templated bf16-MFMA GEMM, B given transposed: C[M][N] = A[M][K] @ Bt[N][K]^T
//   mfma_f32_16x16x32_bf16. LDS tiles XOR-swizzled (byte ^= (row&7)<<4).
//   EPI 0: s = bf16( S[n] * sigmoid(val + Bc[n]) )
//   EPI 1: proj = bf16( val * s[m,n] )
//   EPI 2: out  = f32 ( val + bias[n] )
//   EPI 3: split-K partial: blockIdx.y = K-slice; store fp32 raw at slice offset
// ---------------------------------------------------------------------------
template <int BM, int BN, int BK, int WAVES_M, int WAVES_N, bool A_F32, int EPI>
__global__ __launch_bounds__(256) void gemm_bt(
    const void* __restrict__ Ap, const __bf16* __restrict__ Bt,
    void* __restrict__ Cp, const float* __restrict__ e0,
    const float* __restrict__ e1, const __bf16* __restrict__ s_in,
    int Mt, int Nt, int Kt, int kchunk) {
  constexpr int FM = BM / WAVES_M / 16;
  constexpr int FN = BN / WAVES_N / 16;
  static_assert(WAVES_M * WAVES_N == 4, "4 waves");
  static_assert(BK == 64, "row = 128B");
  __shared__ __align__(16) __bf16 As[BM * BK];
  __shared__ __align__(16) __bf16 Bs[BN * BK];
  const int t  = threadIdx.x;
  const int bm = blockIdx.x * BM;
  const int bn = (EPI == 3) ? 0 : blockIdx.y * BN;
  const int k_lo = (EPI == 3) ? blockIdx.y * kchunk : 0;
  const int k_hi = (EPI == 3) ? k_lo + kchunk : Kt;
  const int w = t >> 6, l = t & 63;
  const int wr0 = (w / WAVES_N) * (FM * 16);
  const int wc0 = (w % WAVES_N) * (FN * 16);
  const int lrow = l & 15;
  const int lk   = l >> 4;
  f32x4 acc[FM][FN] = {};

  for (int k0 = k_lo; k0 < k_hi; k0 += BK) {
    if (A_F32) {
      const float* A = (const float*)Ap;
#pragma unroll
      for (int c = t; c < BM * 8; c += 256) {
        const int row = c >> 3, kc = c & 7;
        const float* g = A + (size_t)(bm + row) * Kt + k0 + kc * 8;
        float4 lo = *(const float4*)g;
        float4 hi = *(const float4*)(g + 4);
        bf16x8 v;
        v[0] = (__bf16)lo.x; v[1] = (__bf16)lo.y; v[2] = (__bf16)lo.z; v[3] = (__bf16)lo.w;
        v[4] = (__bf16)hi.x; v[5] = (__bf16)hi.y; v[6] = (__bf16)hi.z; v[7] = (__bf16)hi.w;
        *(bf16x8*)((char*)As + row * 128 + ((kc ^ (row & 7)) * 16)) = v;
      }
    } else {
      const __bf16* A = (const __bf16*)Ap;
#pragma unroll
      for (int c = t; c < BM * 8; c += 256) {
        const int row = c >> 3, kc = c & 7;
        bf16x8 v = *(const bf16x8*)(A + (size_t)(bm + row) * Kt + k0 + kc * 8);
        *(bf16x8*)((char*)As + row * 128 + ((kc ^ (row & 7)) * 16)) = v;
      }
    }
#pragma unroll
    for (int c = t; c < BN * 8; c += 256) {
      const int row = c >> 3, kc = c & 7;
      bf16x8 v = *(const bf16x8*)(Bt + (size_t)(bn + row) * Kt + k0 + kc * 8);
      *(bf16x8*)((char*)Bs + row * 128 + ((kc ^ (row & 7)) * 16)) = v;
    }
    __syncthreads();
#pragma unroll
    for (int kk = 0; kk < BK / 32; ++kk) {
      bf16x8 af[FM], bfr[FN];
#pragma unroll
      for (int mf = 0; mf < FM; ++mf) {
        const int row = wr0 + mf * 16 + lrow;
        af[mf] = *(const bf16x8*)((const char*)As + row * 128 +
                                  (((kk * 4 + lk) ^ (row & 7)) * 16));
      }
#pragma unroll
      for (int nf = 0; nf < FN; ++nf) {
        const int row = wc0 + nf * 16 + lrow;
        bfr[nf] = *(const bf16x8*)((const char*)Bs + row * 128 +
                                   (((kk * 4 + lk) ^ (row & 7)) * 16));
      }
#pragma unroll
      for (int mf = 0; mf < FM; ++mf)
#pragma unroll
        for (int nf = 0; nf < FN; ++nf)
          acc[mf][nf] = __builtin_amdgcn_mfma_f32_16x16x32_bf16(
              af[mf], bfr[nf], acc[mf][nf], 0, 0, 0);
    }
    __syncthreads();
  }

#pragma unroll
  for (int mf = 0; mf < FM; ++mf) {
#pragma unroll
    for (int nf = 0; nf < FN; ++nf) {
#pragma unroll
      for (int r = 0; r < 4; ++r) {
        const int m = bm + wr0 + mf * 16 + (l >> 4) * 4 + r;
        const int n = bn + wc0 + nf * 16 + (l & 15);
        const float val = acc[mf][nf][r];
        if (EPI == 0) {
          const float h  = val + e1[n];
          const float sg = 1.0f / (1.0f + __expf(-h));
          ((__bf16*)Cp)[(size_t)m * Nt + n] = (__bf16)(e0[n] * sg);
        } else if (EPI == 1) {
          const float sv = (float)s_in[(size_t)m * Nt + n];
          ((__bf16*)Cp)[(size_t)m * Nt + n] = (__bf16)(val * sv);
        } else if (EPI == 2) {
          ((float*)Cp)[(size_t)m * Nt + n] = val + e0[n];
        } else {
          ((float*)Cp)[(size_t)blockIdx.y * Mt * Nt + (size_t)m * Nt + n] = val;
        }
      }
    }
  }
}

// ---------------------------------------------------------------------------
// Reduce: proj[i] = bf16( (sum_s part[s][i]) * s_in[i] ), 4 elems/thread
// ---------------------------------------------------------------------------
__global__ __launch_bounds__(256) void k_reduce(
    const float* __restrict__ part, const __bf16* __restrict__ s_in,
    __bf16* __restrict__ proj, int split) {
  constexpr size_t MN = (size_t)Bdim * RANK;
  const size_t i4 = ((size_t)blockIdx.x * 256 + threadIdx.x) * 4;
  if (i4 >= MN) return;
  float4 acc = *(const float4*)(part + i4);
  for (int sl = 1; sl < split; ++sl) {
    float4 v = *(const float4*)(part + (size_t)sl * MN + i4);
    acc.x += v.x; acc.y += v.y; acc.z += v.z; acc.w += v.w;
  }
  bf16x4 sv = *(const bf16x4*)(s_in + i4);
  bf16x4 o;
  o[0] = (__bf16)(acc.x * (float)sv[0]);
  o[1] = (__bf16)(acc.y * (float)sv[1]);
  o[2] = (__bf16)(acc.z * (float)sv[2]);
  o[3] = (__bf16)(acc.w * (float)sv[3]);
  *(bf16x4*)(proj + i4) = o;
}

}  // namespace

extern "C" void kernel_launch(void* const* d_in, const int* in_sizes, int n_in,
                              void* d_out, int out_size, void* d_ws, size_t ws_size,
                              hipStream_t stream) {
  const float* inputs  = (const float*)d_in[0];  // [4096, 2048]
  const float* context = (const float*)d_in[1];  // [4096, 512]
  const float* U       = (const float*)d_in[2];  // [2048, 256]
  const float* S       = (const float*)d_in[3];  // [256]
  const float* V       = (const float*)d_in[4];  // [2048, 256]
  const float* W       = (const float*)d_in[5];  // [512, 256]
  const float* Bc      = (const float*)d_in[6];  // [256]
  const float* bias    = (const float*)d_in[7];  // [2048]
  float* out = (float*)d_out;                    // [4096, 2048]

  char* ws = (char*)d_ws;
  __bf16* Ut   = (__bf16*)(ws);                       // 256x2048  (1 MB)
  __bf16* Wt   = (__bf16*)(ws + 1048576);             // 256x512   (256 KB)
  __bf16* Vb   = (__bf16*)(ws + 1310720);             // 2048x256  (1 MB)
  __bf16* sbuf = (__bf16*)(ws + 2359296);             // 4096x256  (2 MB)
  __bf16* proj = (__bf16*)(ws + 4456448);             // 4096x256  (2 MB)
  float*  part = (float*)(ws + 6553600);              // split x 4 MB
  const size_t base = 6553600;
  const size_t slice = (size_t)Bdim * RANK * sizeof(float);  // 4 MB

  // Pick largest split-K factor whose partial buffer fits in ws (deterministic).
  int split = 0;
  for (int cand : {8, 4, 2}) {
    if (base + (size_t)cand * slice <= ws_size) { split = cand; break; }
  }

  k_prep<<<dim3(128, 3), 256, 0, stream>>>(U, W, V, Ut, Wt, Vb);

  // s = bf16( S * sigmoid(ctx @ W + Bc) )      [4096 x 256], K=512
  gemm_bt<32, 64, 64, 2, 2, true, 0><<<dim3(Bdim / 32, RANK / 64), 256, 0, stream>>>(
      context, Wt, sbuf, S, Bc, nullptr, Bdim, RANK, D_CTX, 0);

  if (split > 0) {
    // xU partials: [split][4096][256] fp32, K-chunk = 2048/split
    gemm_bt<32, 256, 64, 1, 4, true, 3><<<dim3(Bdim / 32, split), 256, 0, stream>>>(
        inputs, Ut, part, nullptr, nullptr, nullptr, Bdim, RANK, D_IN, D_IN / split);
    // proj = bf16( (sum partials) * s )
    k_reduce<<<dim3((Bdim * RANK) / (256 * 4)), 256, 0, stream>>>(part, sbuf, proj, split);
  } else {
    // fallback: fused, BN=64 for block-count (x re-read via L3)
    gemm_bt<32, 64, 64, 2, 2, true, 1><<<dim3(Bdim / 32, RANK / 64), 256, 0, stream>>>(
        inputs, Ut, proj, nullptr, nullptr, sbuf, Bdim, RANK, D_IN, 0);
  }

  // out = proj @ V^T + bias                    [4096 x 2048], K=256
  gemm_bt<128, 128, 64, 2, 2, false, 2><<<dim3(Bdim / 128, UNITS / 128), 256, 0, stream>>>(
      proj, Vb, out, bias, nullptr, nullptr, Bdim, UNITS, RANK, 0);
}

// Round 4
// 61.843 us; speedup vs baseline: 3.3794x; 1.0528x over previous
//
#include <hip/hip_runtime.h>
#include <math.h>

namespace {

constexpr int Bdim  = 4096;
constexpr int D_IN  = 2048;
constexpr int D_CTX = 512;
constexpr int UNITS = 2048;
constexpr int RANK  = 256;
constexpr int SPLIT = 8;

typedef __bf16 bf16x8 __attribute__((ext_vector_type(8)));
typedef float  f32x4  __attribute__((ext_vector_type(4)));

// ---------------------------------------------------------------------------
// Prep: Ut[256][2048] = bf16(U^T), Wt[256][512] = bf16(W^T)
// ---------------------------------------------------------------------------
__global__ __launch_bounds__(256) void k_prep(
    const float* __restrict__ U, const float* __restrict__ W,
    __bf16* __restrict__ Ut, __bf16* __restrict__ Wt) {
  const int job = blockIdx.y;
  const int t = threadIdx.x;
  const float* src = job ? W : U;
  __bf16* dst      = job ? Wt : Ut;
  const int K = job ? D_CTX : D_IN;   // rows of src
  const int tilesK = K / 64;
  const int tid = blockIdx.x;
  if (tid >= tilesK * 4) return;      // N=256 -> 4 col tiles
  const int k0 = (tid % tilesK) * 64;
  const int n0 = (tid / tilesK) * 64;
  __shared__ __bf16 T[64][72];        // [n][k], pitch 144B (16B-aligned)
  const int i  = t >> 4;              // src row in tile (step 16)
  const int j4 = (t & 15) * 4;        // src col
  for (int ii = i; ii < 64; ii += 16) {
    float4 v = *(const float4*)(src + (size_t)(k0 + ii) * RANK + n0 + j4);
    T[j4 + 0][ii] = (__bf16)v.x;
    T[j4 + 1][ii] = (__bf16)v.y;
    T[j4 + 2][ii] = (__bf16)v.z;
    T[j4 + 3][ii] = (__bf16)v.w;
  }
  __syncthreads();
  const int jj = t >> 3;              // out row in tile (step 32)
  const int c  = t & 7;               // 16B chunk
  for (int j2 = jj; j2 < 64; j2 += 32) {
    bf16x8 v = *(const bf16x8*)&T[j2][c * 8];
    *(bf16x8*)(dst + (size_t)(n0 + j2) * K + k0 + c * 8) = v;
  }
}

// ---------------------------------------------------------------------------
// Templated bf16-MFMA GEMM, B transposed: C[M][N] = A[M][K] @ Bt[N][K]^T
//   mfma_f32_16x16x32_bf16. LDS tiles XOR-swizzled (byte ^= (row&7)<<4).
//   A_F32 / B_F32: stage operand from fp32 global with in-register convert.
//   EPI 2: out  = f32( val + bias[n] )
//   EPI 3: split-K partial: blockIdx.y = K-slice; bf16 partial at slice sl
//   EPI 4: gate+reduce: proj = bf16( (sum_sl part) * S[n]*sigmoid(val+Bc[n]) )
// ---------------------------------------------------------------------------
template <int BM, int BN, int BK, int WAVES_M, int WAVES_N,
          bool A_F32, bool B_F32, int EPI>
__global__ __launch_bounds__(256) void gemm_bt(
    const void* __restrict__ Ap, const void* __restrict__ Btp,
    void* __restrict__ Cp, const float* __restrict__ e0,
    const float* __restrict__ e1, const __bf16* __restrict__ part_in,
    int Mt, int Nt, int Kt, int kchunk) {
  constexpr int FM = BM / WAVES_M / 16;
  constexpr int FN = BN / WAVES_N / 16;
  static_assert(WAVES_M * WAVES_N == 4, "4 waves");
  static_assert(BK == 64, "row = 128B");
  static_assert(EPI != 4 || (BM * BN * 4 <= BN * BK * 2), "red fits in Bs");
  __shared__ __align__(16) __bf16 As[BM * BK];
  __shared__ __align__(16) __bf16 Bs[BN * BK];
  const int t  = threadIdx.x;
  const int bm = blockIdx.x * BM;
  const int bn = (EPI == 3) ? 0 : blockIdx.y * BN;
  const int k_lo = (EPI == 3) ? blockIdx.y * kchunk : 0;
  const int k_hi = (EPI == 3) ? k_lo + kchunk : Kt;
  const int w = t >> 6, l = t & 63;
  const int wr0 = (w / WAVES_N) * (FM * 16);
  const int wc0 = (w % WAVES_N) * (FN * 16);
  const int lrow = l & 15;
  const int lk   = l >> 4;
  f32x4 acc[FM][FN] = {};

  for (int k0 = k_lo; k0 < k_hi; k0 += BK) {
    if (A_F32) {
      const float* A = (const float*)Ap;
#pragma unroll
      for (int c = t; c < BM * 8; c += 256) {
        const int row = c >> 3, kc = c & 7;
        const float* g = A + (size_t)(bm + row) * Kt + k0 + kc * 8;
        float4 lo = *(const float4*)g;
        float4 hi = *(const float4*)(g + 4);
        bf16x8 v;
        v[0] = (__bf16)lo.x; v[1] = (__bf16)lo.y; v[2] = (__bf16)lo.z; v[3] = (__bf16)lo.w;
        v[4] = (__bf16)hi.x; v[5] = (__bf16)hi.y; v[6] = (__bf16)hi.z; v[7] = (__bf16)hi.w;
        *(bf16x8*)((char*)As + row * 128 + ((kc ^ (row & 7)) * 16)) = v;
      }
    } else {
      const __bf16* A = (const __bf16*)Ap;
#pragma unroll
      for (int c = t; c < BM * 8; c += 256) {
        const int row = c >> 3, kc = c & 7;
        bf16x8 v = *(const bf16x8*)(A + (size_t)(bm + row) * Kt + k0 + kc * 8);
        *(bf16x8*)((char*)As + row * 128 + ((kc ^ (row & 7)) * 16)) = v;
      }
    }
    if (B_F32) {
      const float* B = (const float*)Btp;
#pragma unroll
      for (int c = t; c < BN * 8; c += 256) {
        const int row = c >> 3, kc = c & 7;
        const float* g = B + (size_t)(bn + row) * Kt + k0 + kc * 8;
        float4 lo = *(const float4*)g;
        float4 hi = *(const float4*)(g + 4);
        bf16x8 v;
        v[0] = (__bf16)lo.x; v[1] = (__bf16)lo.y; v[2] = (__bf16)lo.z; v[3] = (__bf16)lo.w;
        v[4] = (__bf16)hi.x; v[5] = (__bf16)hi.y; v[6] = (__bf16)hi.z; v[7] = (__bf16)hi.w;
        *(bf16x8*)((char*)Bs + row * 128 + ((kc ^ (row & 7)) * 16)) = v;
      }
    } else {
      const __bf16* B = (const __bf16*)Btp;
#pragma unroll
      for (int c = t; c < BN * 8; c += 256) {
        const int row = c >> 3, kc = c & 7;
        bf16x8 v = *(const bf16x8*)(B + (size_t)(bn + row) * Kt + k0 + kc * 8);
        *(bf16x8*)((char*)Bs + row * 128 + ((kc ^ (row & 7)) * 16)) = v;
      }
    }
    __syncthreads();
#pragma unroll
    for (int kk = 0; kk < BK / 32; ++kk) {
      bf16x8 af[FM], bfr[FN];
#pragma unroll
      for (int mf = 0; mf < FM; ++mf) {
        const int row = wr0 + mf * 16 + lrow;
        af[mf] = *(const bf16x8*)((const char*)As + row * 128 +
                                  (((kk * 4 + lk) ^ (row & 7)) * 16));
      }
#pragma unroll
      for (int nf = 0; nf < FN; ++nf) {
        const int row = wc0 + nf * 16 + lrow;
        bfr[nf] = *(const bf16x8*)((const char*)Bs + row * 128 +
                                   (((kk * 4 + lk) ^ (row & 7)) * 16));
      }
#pragma unroll
      for (int mf = 0; mf < FM; ++mf)
#pragma unroll
        for (int nf = 0; nf < FN; ++nf)
          acc[mf][nf] = __builtin_amdgcn_mfma_f32_16x16x32_bf16(
              af[mf], bfr[nf], acc[mf][nf], 0, 0, 0);
    }
    __syncthreads();
  }

  float* red = (float*)Bs;  // EPI==4: reuse Bs as f32 [BM][BN] reduce buffer
  if (EPI == 4) {
    // Cooperative, fully-coalesced reduce of bf16 partials into LDS.
    const int row = t >> 3;            // 0..31 (BM=32)
    const int ch  = (t & 7) * 8;       // 0..56 (BN=64, 8 bf16 per thread)
    float racc[8] = {};
    for (int sl = 0; sl < kchunk; ++sl) {
      bf16x8 v = *(const bf16x8*)(part_in +
                    ((size_t)sl * Mt + bm + row) * Nt + bn + ch);
#pragma unroll
      for (int i = 0; i < 8; ++i) racc[i] += (float)v[i];
    }
#pragma unroll
    for (int i = 0; i < 8; ++i) red[row * BN + ch + i] = racc[i];
    __syncthreads();
  }

#pragma unroll
  for (int mf = 0; mf < FM; ++mf) {
#pragma unroll
    for (int nf = 0; nf < FN; ++nf) {
#pragma unroll
      for (int r = 0; r < 4; ++r) {
        const int lm = wr0 + mf * 16 + lk * 4 + r;
        const int ln = wc0 + nf * 16 + lrow;
        const int m = bm + lm;
        const int n = bn + ln;
        const float val = acc[mf][nf][r];
        if (EPI == 2) {
          ((float*)Cp)[(size_t)m * Nt + n] = val + e0[n];
        } else if (EPI == 3) {
          ((__bf16*)Cp)[(size_t)blockIdx.y * Mt * Nt + (size_t)m * Nt + n] =
              (__bf16)val;
        } else {  // EPI == 4
          const float h    = val + e1[n];
          const float sval = e0[n] / (1.0f + __expf(-h));
          ((__bf16*)Cp)[(size_t)m * Nt + n] = (__bf16)(red[lm * BN + ln] * sval);
        }
      }
    }
  }
}

}  // namespace

extern "C" void kernel_launch(void* const* d_in, const int* in_sizes, int n_in,
                              void* d_out, int out_size, void* d_ws, size_t ws_size,
                              hipStream_t stream) {
  const float* inputs  = (const float*)d_in[0];  // [4096, 2048]
  const float* context = (const float*)d_in[1];  // [4096, 512]
  const float* U       = (const float*)d_in[2];  // [2048, 256]
  const float* S       = (const float*)d_in[3];  // [256]
  const float* V       = (const float*)d_in[4];  // [2048, 256]
  const float* W       = (const float*)d_in[5];  // [512, 256]
  const float* Bc      = (const float*)d_in[6];  // [256]
  const float* bias    = (const float*)d_in[7];  // [2048]
  float* out = (float*)d_out;                    // [4096, 2048]

  char* ws = (char*)d_ws;
  __bf16* Ut   = (__bf16*)(ws);                  // 256x2048         (1 MB)
  __bf16* Wt   = (__bf16*)(ws + 1048576);        // 256x512          (256 KB)
  __bf16* proj = (__bf16*)(ws + 1310720);        // 4096x256         (2 MB)
  __bf16* part = (__bf16*)(ws + 3407872);        // SPLIT x4096x256  (16 MB)

  // 1) weight transpose+convert (Ut, Wt)
  k_prep<<<dim3(128, 2), 256, 0, stream>>>(U, W, Ut, Wt);

  // 2) xU bf16 partials: [8][4096][256], K-chunk = 256
  gemm_bt<32, 256, 64, 1, 4, true, false, 3>
      <<<dim3(Bdim / 32, SPLIT), 256, 0, stream>>>(
      inputs, Ut, part, nullptr, nullptr, nullptr, Bdim, RANK, D_IN, D_IN / SPLIT);

  // 3) gate GEMM + fused partial-reduce:
  //    proj = bf16( (sum partials) * S*sigmoid(ctx@W + Bc) )
  gemm_bt<32, 64, 64, 2, 2, true, false, 4>
      <<<dim3(Bdim / 32, RANK / 64), 256, 0, stream>>>(
      context, Wt, proj, S, Bc, part, Bdim, RANK, D_CTX, SPLIT);

  // 4) out = proj @ V^T + bias   (V staged directly from fp32)
  gemm_bt<128, 128, 64, 2, 2, false, true, 2>
      <<<dim3(Bdim / 128, UNITS / 128), 256, 0, stream>>>(
      proj, V, out, bias, nullptr, nullptr, Bdim, UNITS, RANK, 0);
}